// Round 2
// baseline (1490.165 us; speedup 1.0000x reference)
//
#include <hip/hip_runtime.h>

#define N_NODES   100000
#define NPERM_    100000
#define L_        16
#define H_        64
#define G_        1024

// ---------------------------------------------------------------------------
// Transpose W_lrp [4][64][64][16] (k,c,l) -> Wt [4][16][64][64] (l,k,c)
// so the einsum kernel can load W chunks coalesced.
__global__ __launch_bounds__(256) void k_transpose_w(const float* __restrict__ W,
                                                     float* __restrict__ Wt) {
    int o = blockIdx.x * 256 + threadIdx.x;     // 4*16*64*64 = 262144 threads
    int c = o & 63;
    int k = (o >> 6) & 63;
    int l = (o >> 12) & 15;
    int i = o >> 16;
    Wt[o] = W[((((i * 64 + k) * 64) + c) << 4) + l];
}

// ---------------------------------------------------------------------------
// x = node_feat @ atom_W + atom_b        [N,28]@[28,64]
__global__ __launch_bounds__(256) void k_atom(const float* __restrict__ feat,
                                              const float* __restrict__ W,
                                              const float* __restrict__ b,
                                              float* __restrict__ x) {
    __shared__ float Wl[28 * 64];
    __shared__ float bl[64];
    int tid = threadIdx.x;
    for (int t = tid; t < 28 * 64; t += 256) Wl[t] = W[t];
    if (tid < 64) bl[tid] = b[tid];
    __syncthreads();
    int n = blockIdx.x * 4 + (tid >> 6);   // wave-uniform node
    int c = tid & 63;
    if (n >= N_NODES) return;
    const float* fr = feat + n * 28;
    float acc = bl[c];
#pragma unroll
    for (int j = 0; j < 28; ++j) acc = fmaf(fr[j], Wl[j * 64 + c], acc);
    x[n * 64 + c] = acc;
}

// ---------------------------------------------------------------------------
// Fused gather + einsum:  h[d,c] = relu( sum_{l,k} T[d,l,k] * W[k,c,l] + b[c] )
// T[d,l,k] = n2p_val[p]*x[n2p_col[p]][k] + e2p_val[p]*ef[k],  p = d*16+l
// (ef is the constant edge-encoder row: all edge features are 1.)
// Block tile: 128 d-rows x 64 c.  Per-thread: 8 d x 4 c accumulator.
__global__ __launch_bounds__(256) void k_lrp(const float* __restrict__ x,
                                             const int*   __restrict__ n2p_col,
                                             const float* __restrict__ n2p_val,
                                             const float* __restrict__ e2p_val,
                                             const float* __restrict__ edge_W,
                                             const float* __restrict__ edge_b,
                                             const float* __restrict__ Wt,   // [16][64][64] this layer
                                             const float* __restrict__ bl,   // [64]
                                             float* __restrict__ hout) {
    __shared__ float Tl[64][128];   // [k][d]  (writes 2-way, reads broadcast)
    __shared__ float Wl[64 * 64];   // [k][c]
    int tid = threadIdx.x;
    int tx = tid & 15;              // c-group: c = tx*4..tx*4+3
    int ty = tid >> 4;              // d-group: d = ty*8..ty*8+7
    int d0 = blockIdx.x * 128;

    int dl = tid >> 1;              // fill: row 0..127
    int kq = tid & 1;               // fill: k half (32 each)

    // per-thread constant edge-feature slice ef[k], k = kq*32 + 0..31
    float ef[32];
#pragma unroll
    for (int j = 0; j < 8; ++j) {
        float4 ew = *(const float4*)(edge_W + kq * 32 + j * 4);
        float4 eb = *(const float4*)(edge_b + kq * 32 + j * 4);
        ef[j * 4 + 0] = ew.x + eb.x; ef[j * 4 + 1] = ew.y + eb.y;
        ef[j * 4 + 2] = ew.z + eb.z; ef[j * 4 + 3] = ew.w + eb.w;
    }

    float acc[8][4];
#pragma unroll
    for (int m = 0; m < 8; ++m)
#pragma unroll
        for (int n = 0; n < 4; ++n) acc[m][n] = 0.f;

    int  dg = d0 + dl;
    bool drow_ok = (dg < NPERM_);

    for (int l = 0; l < L_; ++l) {
        __syncthreads();
        {   // W chunk, coalesced float4
            const float4* src = (const float4*)(Wt + l * 4096);
            float4*       dst = (float4*)Wl;
#pragma unroll
            for (int t = 0; t < 4; ++t) dst[t * 256 + tid] = src[t * 256 + tid];
        }
        {   // gathered T rows
            int p = dg * L_ + l;
            int col = 0; float vn = 0.f, ve = 0.f;
            if (drow_ok) { col = n2p_col[p]; vn = n2p_val[p]; ve = e2p_val[p]; }
            const float4* xr = (const float4*)(x + (size_t)col * 64 + kq * 32);
#pragma unroll
            for (int j = 0; j < 8; ++j) {
                float4 v = xr[j];
                int kb = kq * 32 + j * 4;
                Tl[kb + 0][dl] = fmaf(vn, v.x, ve * ef[j * 4 + 0]);
                Tl[kb + 1][dl] = fmaf(vn, v.y, ve * ef[j * 4 + 1]);
                Tl[kb + 2][dl] = fmaf(vn, v.z, ve * ef[j * 4 + 2]);
                Tl[kb + 3][dl] = fmaf(vn, v.w, ve * ef[j * 4 + 3]);
            }
        }
        __syncthreads();
#pragma unroll 4
        for (int k = 0; k < 64; ++k) {
            float4 w4 = *(const float4*)(Wl + k * 64 + tx * 4);
            float4 ta = *(const float4*)(&Tl[k][ty * 8]);
            float4 tb = *(const float4*)(&Tl[k][ty * 8 + 4]);
#pragma unroll
            for (int n = 0; n < 4; ++n) {
                float w = (n == 0) ? w4.x : (n == 1) ? w4.y : (n == 2) ? w4.z : w4.w;
                acc[0][n] = fmaf(ta.x, w, acc[0][n]);
                acc[1][n] = fmaf(ta.y, w, acc[1][n]);
                acc[2][n] = fmaf(ta.z, w, acc[2][n]);
                acc[3][n] = fmaf(ta.w, w, acc[3][n]);
                acc[4][n] = fmaf(tb.x, w, acc[4][n]);
                acc[5][n] = fmaf(tb.y, w, acc[5][n]);
                acc[6][n] = fmaf(tb.z, w, acc[6][n]);
                acc[7][n] = fmaf(tb.w, w, acc[7][n]);
            }
        }
    }
    float4 bb = *(const float4*)(bl + tx * 4);
#pragma unroll
    for (int m = 0; m < 8; ++m) {
        int dd = d0 + ty * 8 + m;
        if (dd < NPERM_) {
            float4 o;
            o.x = fmaxf(acc[m][0] + bb.x, 0.f);
            o.y = fmaxf(acc[m][1] + bb.y, 0.f);
            o.z = fmaxf(acc[m][2] + bb.z, 0.f);
            o.w = fmaxf(acc[m][3] + bb.w, 0.f);
            *(float4*)(hout + (size_t)dd * 64 + tx * 4) = o;
        }
    }
}

// ---------------------------------------------------------------------------
// pooled[pool_row[d]] += pool_val[d] * h[d]   (into pre-zeroed x)
__global__ __launch_bounds__(256) void k_scatter(const float* __restrict__ h,
                                                 const int*   __restrict__ prow,
                                                 const float* __restrict__ pval,
                                                 float* __restrict__ xo) {
    int idx = blockIdx.x * 256 + threadIdx.x;
    int d = idx >> 6, c = idx & 63;
    if (d >= NPERM_) return;
    int r = prow[d];
    float v = pval[d];
    atomicAdd(xo + (size_t)r * 64 + c, v * h[(size_t)d * 64 + c]);
}

// ---------------------------------------------------------------------------
// x[n] *= ( relu(degs[n]*dn0W + dn0b) @ dn1W + dn1b )
// Block tile: 64 nodes x 64 c, K=128, per-thread 4x4 accumulator.
__global__ __launch_bounds__(256) void k_factor(float* __restrict__ x,
                                                const float* __restrict__ degs,
                                                const float* __restrict__ A,   // dn0W [128]
                                                const float* __restrict__ Bb,  // dn0b [128]
                                                const float* __restrict__ W1,  // dn1W [128][64]
                                                const float* __restrict__ b1) {
    __shared__ float Hl[128][64];   // [j][node]
    __shared__ float Wl[128 * 64];  // [j][c]
    int tid = threadIdx.x;
    int tx = tid & 15, ty = tid >> 4;
    int d0 = blockIdx.x * 64;
    {
        const float4* src = (const float4*)W1;
        float4*       dst = (float4*)Wl;
#pragma unroll
        for (int t = 0; t < 8; ++t) dst[t * 256 + tid] = src[t * 256 + tid];
    }
    int dl = tid >> 2, jq = tid & 3;
    int n = d0 + dl;
    float dg = (n < N_NODES) ? degs[n] : 0.f;
#pragma unroll
    for (int jj = 0; jj < 32; ++jj) {
        int j = jq * 32 + jj;
        Hl[j][dl] = fmaxf(fmaf(dg, A[j], Bb[j]), 0.f);
    }
    __syncthreads();
    float acc[4][4];
#pragma unroll
    for (int m = 0; m < 4; ++m)
#pragma unroll
        for (int q = 0; q < 4; ++q) acc[m][q] = 0.f;
#pragma unroll 4
    for (int k = 0; k < 128; ++k) {
        float4 w4 = *(const float4*)(Wl + k * 64 + tx * 4);
        float4 t4 = *(const float4*)(&Hl[k][ty * 4]);
#pragma unroll
        for (int q = 0; q < 4; ++q) {
            float w = (q == 0) ? w4.x : (q == 1) ? w4.y : (q == 2) ? w4.z : w4.w;
            acc[0][q] = fmaf(t4.x, w, acc[0][q]);
            acc[1][q] = fmaf(t4.y, w, acc[1][q]);
            acc[2][q] = fmaf(t4.z, w, acc[2][q]);
            acc[3][q] = fmaf(t4.w, w, acc[3][q]);
        }
    }
    float4 bb = *(const float4*)(b1 + tx * 4);
#pragma unroll
    for (int m = 0; m < 4; ++m) {
        int nn = d0 + ty * 4 + m;
        if (nn < N_NODES) {
            float4 xv = *(float4*)(x + (size_t)nn * 64 + tx * 4);
            xv.x *= acc[m][0] + bb.x;
            xv.y *= acc[m][1] + bb.y;
            xv.z *= acc[m][2] + bb.z;
            xv.w *= acc[m][3] + bb.w;
            *(float4*)(x + (size_t)nn * 64 + tx * 4) = xv;
        }
    }
}

// ---------------------------------------------------------------------------
// global mean pool over graphs (batch is sorted, but atomics are fine here)
__global__ __launch_bounds__(256) void k_gpool(const float* __restrict__ x,
                                               const int* __restrict__ batch,
                                               float* __restrict__ out,
                                               float* __restrict__ cnt) {
    int idx = blockIdx.x * 256 + threadIdx.x;
    int n = idx >> 6, c = idx & 63;
    if (n >= N_NODES) return;
    int g = batch[n];
    atomicAdd(out + (size_t)g * 64 + c, x[(size_t)n * 64 + c]);
    if (c == 0) atomicAdd(cnt + g, 1.f);
}

__global__ __launch_bounds__(256) void k_gdiv(float* __restrict__ out,
                                              const float* __restrict__ cnt) {
    int idx = blockIdx.x * 256 + threadIdx.x;
    if (idx >= G_ * 64) return;
    out[idx] /= fmaxf(cnt[idx >> 6], 1.f);
}

// ---------------------------------------------------------------------------
extern "C" void kernel_launch(void* const* d_in, const int* in_sizes, int n_in,
                              void* d_out, int out_size, void* d_ws, size_t ws_size,
                              hipStream_t stream) {
    const float* node_feat = (const float*)d_in[0];
    const float* degs      = (const float*)d_in[1];
    const int*   batch     = (const int*)  d_in[2];
    const int*   n2p_col   = (const int*)  d_in[4];
    const float* n2p_val   = (const float*)d_in[5];
    const float* e2p_val   = (const float*)d_in[8];
    const int*   pool_row  = (const int*)  d_in[9];
    const float* pool_val  = (const float*)d_in[11];
    const float* atom_W    = (const float*)d_in[12];
    const float* atom_b    = (const float*)d_in[13];
    const float* edge_W    = (const float*)d_in[14];
    const float* edge_b    = (const float*)d_in[15];
    const float* W_lrp     = (const float*)d_in[16];
    const float* b_lrp     = (const float*)d_in[17];
    const float* dn0_W     = (const float*)d_in[18];
    const float* dn0_b     = (const float*)d_in[19];
    const float* dn1_W     = (const float*)d_in[20];
    const float* dn1_b     = (const float*)d_in[21];

    char*  ws  = (char*)d_ws;
    float* x   = (float*)ws;                            // N*64   f32 = 25.6 MB
    float* h   = (float*)(ws + 25600000);               // NPERM*64    = 25.6 MB
    float* Wt  = (float*)(ws + 51200000);               // 4*16*64*64  = 1 MB
    float* cnt = (float*)(ws + 52248576);               // G

    hipLaunchKernelGGL(k_transpose_w, dim3(1024), dim3(256), 0, stream, W_lrp, Wt);
    hipLaunchKernelGGL(k_atom, dim3(25000), dim3(256), 0, stream,
                       node_feat, atom_W, atom_b, x);
    for (int i = 0; i < 4; ++i) {
        hipLaunchKernelGGL(k_lrp, dim3(782), dim3(256), 0, stream,
                           x, n2p_col, n2p_val, e2p_val, edge_W, edge_b,
                           Wt + (size_t)i * 65536, b_lrp + i * 64, h);
        hipMemsetAsync(x, 0, (size_t)N_NODES * 64 * 4, stream);
        hipLaunchKernelGGL(k_scatter, dim3(25000), dim3(256), 0, stream,
                           h, pool_row, pool_val, x);
        hipLaunchKernelGGL(k_factor, dim3(1563), dim3(256), 0, stream,
                           x, degs, dn0_W + i * 128, dn0_b + i * 128,
                           dn1_W + i * 8192, dn1_b + i * 64);
    }
    hipMemsetAsync(d_out, 0, (size_t)G_ * 64 * 4, stream);
    hipMemsetAsync(cnt, 0, G_ * 4, stream);
    hipLaunchKernelGGL(k_gpool, dim3(25000), dim3(256), 0, stream,
                       x, batch, (float*)d_out, cnt);
    hipLaunchKernelGGL(k_gdiv, dim3(256), dim3(256), 0, stream,
                       (float*)d_out, cnt);
}

// Round 4
// 1486.855 us; speedup vs baseline: 1.0022x; 1.0022x over previous
//
#include <hip/hip_runtime.h>

#define N_NODES   100000
#define NPERM_    100000
#define L_        16
#define H_        64
#define G_        1024

// ---------------------------------------------------------------------------
// Transpose W_lrp [4][64][64][16] (k,c,l) -> Wt [4][16][64][64] (l,k,c)
__global__ __launch_bounds__(256) void k_transpose_w(const float* __restrict__ W,
                                                     float* __restrict__ Wt) {
    int o = blockIdx.x * 256 + threadIdx.x;     // 4*16*64*64 = 262144 threads
    int c = o & 63;
    int k = (o >> 6) & 63;
    int l = (o >> 12) & 15;
    int i = o >> 16;
    Wt[o] = W[((((i * 64 + k) * 64) + c) << 4) + l];
}

// ---------------------------------------------------------------------------
// x = node_feat @ atom_W + atom_b        [N,28]@[28,64]
__global__ __launch_bounds__(256) void k_atom(const float* __restrict__ feat,
                                              const float* __restrict__ W,
                                              const float* __restrict__ b,
                                              float* __restrict__ x) {
    __shared__ float Wl[28 * 64];
    __shared__ float bl[64];
    int tid = threadIdx.x;
    for (int t = tid; t < 28 * 64; t += 256) Wl[t] = W[t];
    if (tid < 64) bl[tid] = b[tid];
    __syncthreads();
    int n = blockIdx.x * 4 + (tid >> 6);
    int c = tid & 63;
    if (n >= N_NODES) return;
    const float* fr = feat + n * 28;
    float acc = bl[c];
#pragma unroll
    for (int j = 0; j < 28; ++j) acc = fmaf(fr[j], Wl[j * 64 + c], acc);
    x[n * 64 + c] = acc;
}

// ---------------------------------------------------------------------------
// Fused gather + einsum + relu + pool-scatter.
//   h[d,c] = relu( sum_{l,k} (vn*x[col[d,l]][k] + ve*ef[k]) * W[k,c,l] + b[c] )
//   xout[pool_row[d]] += pool_val[d] * h[d]     (atomic, xout pre-zeroed)
// Software-pipelined: col chain prefetched 2 deep; x-row + W chunk for l+1
// loaded into registers during compute of l.
__global__ __launch_bounds__(256) void k_lrp(const float* __restrict__ x,
                                             const int*   __restrict__ n2p_col,
                                             const float* __restrict__ n2p_val,
                                             const float* __restrict__ e2p_val,
                                             const float* __restrict__ edge_W,
                                             const float* __restrict__ edge_b,
                                             const float* __restrict__ Wt,   // [16][64][64]
                                             const float* __restrict__ bl,   // [64]
                                             const int*   __restrict__ pool_row,
                                             const float* __restrict__ pool_val,
                                             float* __restrict__ xout) {
    __shared__ float Tl[64][128];   // [k][d]
    __shared__ float Wl[64 * 64];   // [k][c]
    __shared__ float efs[64];       // edge-encoder constant row
    int tid = threadIdx.x;
    int tx = tid & 15;              // c-group
    int ty = tid >> 4;              // d-group
    int d0 = blockIdx.x * 128;
    int dl = tid >> 1;              // fill row 0..127
    int kq = tid & 1;               // fill k-half
    int dg = d0 + dl;
    int dsafe = (dg < NPERM_) ? dg : 0;
    size_t pbase = (size_t)dsafe * 16;

    if (tid < 64) efs[tid] = edge_W[tid] + edge_b[tid];

    float acc[8][4];
#pragma unroll
    for (int m = 0; m < 8; ++m)
#pragma unroll
        for (int n = 0; n < 4; ++n) acc[m][n] = 0.f;

    // ---- prologue: stage l=0, and col for l=1 (2-deep col pipeline)
    float4 wv[4], xv[8];
    int   colN2 = n2p_col[pbase + 1];
    float vnN   = n2p_val[pbase + 0];
    float veN   = e2p_val[pbase + 0];
    {
        int col0 = n2p_col[pbase + 0];
        const float4* ws0 = (const float4*)Wt;
#pragma unroll
        for (int t = 0; t < 4; ++t) wv[t] = ws0[t * 256 + tid];
        const float4* xr = (const float4*)(x + (size_t)col0 * 64 + kq * 32);
#pragma unroll
        for (int j = 0; j < 8; ++j) xv[j] = xr[j];
    }
    __syncthreads();   // efs visible

    for (int l = 0; l < L_; ++l) {
        float vn = vnN, ve = veN;
        __syncthreads();           // previous compute done, LDS free
        {   // store staged regs -> LDS
            float4* wd = (float4*)Wl;
#pragma unroll
            for (int t = 0; t < 4; ++t) wd[t * 256 + tid] = wv[t];
#pragma unroll
            for (int j = 0; j < 8; ++j) {
                int kb = kq * 32 + j * 4;
                float4 v = xv[j];
                Tl[kb + 0][dl] = fmaf(vn, v.x, ve * efs[kb + 0]);
                Tl[kb + 1][dl] = fmaf(vn, v.y, ve * efs[kb + 1]);
                Tl[kb + 2][dl] = fmaf(vn, v.z, ve * efs[kb + 2]);
                Tl[kb + 3][dl] = fmaf(vn, v.w, ve * efs[kb + 3]);
            }
        }
        __syncthreads();           // tiles visible
        if (l < 15) {              // prefetch next l (hidden under compute)
            const float4* ws2 = (const float4*)(Wt + (l + 1) * 4096);
#pragma unroll
            for (int t = 0; t < 4; ++t) wv[t] = ws2[t * 256 + tid];
            const float4* xr = (const float4*)(x + (size_t)colN2 * 64 + kq * 32);
#pragma unroll
            for (int j = 0; j < 8; ++j) xv[j] = xr[j];
            vnN = n2p_val[pbase + l + 1];
            veN = e2p_val[pbase + l + 1];
            if (l < 14) colN2 = n2p_col[pbase + l + 2];
        }
#pragma unroll 4
        for (int k = 0; k < 64; ++k) {
            float4 w4 = *(const float4*)(Wl + k * 64 + tx * 4);
            float4 ta = *(const float4*)(&Tl[k][ty * 8]);
            float4 tb = *(const float4*)(&Tl[k][ty * 8 + 4]);
#pragma unroll
            for (int n = 0; n < 4; ++n) {
                float w = (n == 0) ? w4.x : (n == 1) ? w4.y : (n == 2) ? w4.z : w4.w;
                acc[0][n] = fmaf(ta.x, w, acc[0][n]);
                acc[1][n] = fmaf(ta.y, w, acc[1][n]);
                acc[2][n] = fmaf(ta.z, w, acc[2][n]);
                acc[3][n] = fmaf(ta.w, w, acc[3][n]);
                acc[4][n] = fmaf(tb.x, w, acc[4][n]);
                acc[5][n] = fmaf(tb.y, w, acc[5][n]);
                acc[6][n] = fmaf(tb.z, w, acc[6][n]);
                acc[7][n] = fmaf(tb.w, w, acc[7][n]);
            }
        }
    }
    // ---- epilogue: relu + fused pool scatter
    float4 bb = *(const float4*)(bl + tx * 4);
#pragma unroll
    for (int m = 0; m < 8; ++m) {
        int dd = d0 + ty * 8 + m;
        if (dd < NPERM_) {
            int   r  = pool_row[dd];
            float pv = pool_val[dd];
            float* dst = xout + (size_t)r * 64 + tx * 4;
            atomicAdd(dst + 0, pv * fmaxf(acc[m][0] + bb.x, 0.f));
            atomicAdd(dst + 1, pv * fmaxf(acc[m][1] + bb.y, 0.f));
            atomicAdd(dst + 2, pv * fmaxf(acc[m][2] + bb.z, 0.f));
            atomicAdd(dst + 3, pv * fmaxf(acc[m][3] + bb.w, 0.f));
        }
    }
}

// ---------------------------------------------------------------------------
// x[n] *= ( relu(degs[n]*dn0W + dn0b) @ dn1W + dn1b )
__global__ __launch_bounds__(256) void k_factor(float* __restrict__ x,
                                                const float* __restrict__ degs,
                                                const float* __restrict__ A,   // dn0W [128]
                                                const float* __restrict__ Bb,  // dn0b [128]
                                                const float* __restrict__ W1,  // dn1W [128][64]
                                                const float* __restrict__ b1) {
    __shared__ float Hl[128][64];
    __shared__ float Wl[128 * 64];
    int tid = threadIdx.x;
    int tx = tid & 15, ty = tid >> 4;
    int d0 = blockIdx.x * 64;
    {
        const float4* src = (const float4*)W1;
        float4*       dst = (float4*)Wl;
#pragma unroll
        for (int t = 0; t < 8; ++t) dst[t * 256 + tid] = src[t * 256 + tid];
    }
    int dl = tid >> 2, jq = tid & 3;
    int n = d0 + dl;
    float dg = (n < N_NODES) ? degs[n] : 0.f;
#pragma unroll
    for (int jj = 0; jj < 32; ++jj) {
        int j = jq * 32 + jj;
        Hl[j][dl] = fmaxf(fmaf(dg, A[j], Bb[j]), 0.f);
    }
    __syncthreads();
    float acc[4][4];
#pragma unroll
    for (int m = 0; m < 4; ++m)
#pragma unroll
        for (int q = 0; q < 4; ++q) acc[m][q] = 0.f;
#pragma unroll 4
    for (int k = 0; k < 128; ++k) {
        float4 w4 = *(const float4*)(Wl + k * 64 + tx * 4);
        float4 t4 = *(const float4*)(&Hl[k][ty * 4]);
#pragma unroll
        for (int q = 0; q < 4; ++q) {
            float w = (q == 0) ? w4.x : (q == 1) ? w4.y : (q == 2) ? w4.z : w4.w;
            acc[0][q] = fmaf(t4.x, w, acc[0][q]);
            acc[1][q] = fmaf(t4.y, w, acc[1][q]);
            acc[2][q] = fmaf(t4.z, w, acc[2][q]);
            acc[3][q] = fmaf(t4.w, w, acc[3][q]);
        }
    }
    float4 bb = *(const float4*)(b1 + tx * 4);
#pragma unroll
    for (int m = 0; m < 4; ++m) {
        int nn = d0 + ty * 4 + m;
        if (nn < N_NODES) {
            float4 xv = *(float4*)(x + (size_t)nn * 64 + tx * 4);
            xv.x *= acc[m][0] + bb.x;
            xv.y *= acc[m][1] + bb.y;
            xv.z *= acc[m][2] + bb.z;
            xv.w *= acc[m][3] + bb.w;
            *(float4*)(x + (size_t)nn * 64 + tx * 4) = xv;
        }
    }
}

// ---------------------------------------------------------------------------
// Segmented mean-pool: batch is SORTED, so each wave scans a contiguous
// 64-node run, accumulates per-graph partial sums, flushes one atomic per
// graph boundary (~2.5 per wave) instead of one per node.
__global__ __launch_bounds__(256) void k_gpool(const float* __restrict__ x,
                                               const int* __restrict__ batch,
                                               float* __restrict__ out,
                                               float* __restrict__ cnt) {
    int wave = (blockIdx.x * 256 + threadIdx.x) >> 6;
    int lane = threadIdx.x & 63;
    int n0 = wave * 64;
    if (n0 >= N_NODES) return;
    int n1 = min(n0 + 64, N_NODES);
    int g = batch[n0];
    float s = 0.f, c = 0.f;
    for (int n = n0; n < n1; ++n) {
        int gn = batch[n];
        if (gn != g) {
            atomicAdd(out + (size_t)g * 64 + lane, s);
            if (lane == 0) atomicAdd(cnt + g, c);
            s = 0.f; c = 0.f; g = gn;
        }
        s += x[(size_t)n * 64 + lane];
        c += 1.f;
    }
    atomicAdd(out + (size_t)g * 64 + lane, s);
    if (lane == 0) atomicAdd(cnt + g, c);
}

__global__ __launch_bounds__(256) void k_gdiv(float* __restrict__ out,
                                              const float* __restrict__ cnt) {
    int idx = blockIdx.x * 256 + threadIdx.x;
    if (idx >= G_ * 64) return;
    out[idx] /= fmaxf(cnt[idx >> 6], 1.f);
}

// ---------------------------------------------------------------------------
extern "C" void kernel_launch(void* const* d_in, const int* in_sizes, int n_in,
                              void* d_out, int out_size, void* d_ws, size_t ws_size,
                              hipStream_t stream) {
    const float* node_feat = (const float*)d_in[0];
    const float* degs      = (const float*)d_in[1];
    const int*   batch     = (const int*)  d_in[2];
    const int*   n2p_col   = (const int*)  d_in[4];
    const float* n2p_val   = (const float*)d_in[5];
    const float* e2p_val   = (const float*)d_in[8];
    const int*   pool_row  = (const int*)  d_in[9];
    const float* pool_val  = (const float*)d_in[11];
    const float* atom_W    = (const float*)d_in[12];
    const float* atom_b    = (const float*)d_in[13];
    const float* edge_W    = (const float*)d_in[14];
    const float* edge_b    = (const float*)d_in[15];
    const float* W_lrp     = (const float*)d_in[16];
    const float* b_lrp     = (const float*)d_in[17];
    const float* dn0_W     = (const float*)d_in[18];
    const float* dn0_b     = (const float*)d_in[19];
    const float* dn1_W     = (const float*)d_in[20];
    const float* dn1_b     = (const float*)d_in[21];

    char*  ws  = (char*)d_ws;
    float* x0  = (float*)ws;                            // 25.6 MB
    float* x1  = (float*)(ws + 25600000);               // 25.6 MB
    float* Wt  = (float*)(ws + 51200000);               // 1 MB
    float* cnt = (float*)(ws + 52248576);               // 4 KB

    hipLaunchKernelGGL(k_transpose_w, dim3(1024), dim3(256), 0, stream, W_lrp, Wt);
    hipLaunchKernelGGL(k_atom, dim3(25000), dim3(256), 0, stream,
                       node_feat, atom_W, atom_b, x0);
    float* xin = x0;
    float* xpool = x1;
    for (int i = 0; i < 4; ++i) {
        hipMemsetAsync(xpool, 0, (size_t)N_NODES * 64 * 4, stream);
        hipLaunchKernelGGL(k_lrp, dim3(782), dim3(256), 0, stream,
                           xin, n2p_col, n2p_val, e2p_val, edge_W, edge_b,
                           Wt + (size_t)i * 65536, b_lrp + i * 64,
                           pool_row, pool_val, xpool);
        hipLaunchKernelGGL(k_factor, dim3(1563), dim3(256), 0, stream,
                           xpool, degs, dn0_W + i * 128, dn0_b + i * 128,
                           dn1_W + i * 8192, dn1_b + i * 64);
        float* t = xin; xin = xpool; xpool = t;
    }
    hipMemsetAsync(d_out, 0, (size_t)G_ * 64 * 4, stream);
    hipMemsetAsync(cnt, 0, G_ * 4, stream);
    hipLaunchKernelGGL(k_gpool, dim3(391), dim3(256), 0, stream,
                       xin, batch, (float*)d_out, cnt);
    hipLaunchKernelGGL(k_gdiv, dim3(256), dim3(256), 0, stream,
                       (float*)d_out, cnt);
}

// Round 5
// 1410.307 us; speedup vs baseline: 1.0566x; 1.0543x over previous
//
#include <hip/hip_runtime.h>

#define N_NODES   100000
#define NPERM_    100000
#define L_        16
#define H_        64
#define G_        1024
#define CAP_      24
#define OVF_MAX   4096

// ---------------------------------------------------------------------------
// Transpose W_lrp [4][64][64][16] (k,c,l) -> Wt [4][16][64][64] (l,k,c)
__global__ __launch_bounds__(256) void k_transpose_w(const float* __restrict__ W,
                                                     float* __restrict__ Wt) {
    int o = blockIdx.x * 256 + threadIdx.x;     // 262144 threads
    int c = o & 63;
    int k = (o >> 6) & 63;
    int l = (o >> 12) & 15;
    int i = o >> 16;
    Wt[o] = W[((((i * 64 + k) * 64) + c) << 4) + l];
}

// ---------------------------------------------------------------------------
// x = node_feat @ atom_W + atom_b        [N,28]@[28,64]
__global__ __launch_bounds__(256) void k_atom(const float* __restrict__ feat,
                                              const float* __restrict__ W,
                                              const float* __restrict__ b,
                                              float* __restrict__ x) {
    __shared__ float Wl[28 * 64];
    __shared__ float bl[64];
    int tid = threadIdx.x;
    for (int t = tid; t < 28 * 64; t += 256) Wl[t] = W[t];
    if (tid < 64) bl[tid] = b[tid];
    __syncthreads();
    int n = blockIdx.x * 4 + (tid >> 6);
    int c = tid & 63;
    if (n >= N_NODES) return;
    const float* fr = feat + n * 28;
    float acc = bl[c];
#pragma unroll
    for (int j = 0; j < 28; ++j) acc = fmaf(fr[j], Wl[j * 64 + c], acc);
    x[n * 64 + c] = acc;
}

// ---------------------------------------------------------------------------
// Bucket subgraphs by pool target node (pool_row is layer-invariant; built
// once per launch).  CAP=24 covers the balls-in-bins max (~10) with huge
// margin; overflow goes to a list handled in k_pool_factor for correctness.
__global__ __launch_bounds__(256) void k_bucket(const int* __restrict__ prow,
                                                int* __restrict__ cntn,
                                                int* __restrict__ bucket,
                                                int* __restrict__ ovf,
                                                int* __restrict__ ovfc) {
    int d = blockIdx.x * 256 + threadIdx.x;
    if (d >= NPERM_) return;
    int n = prow[d];
    int s = atomicAdd(cntn + n, 1);
    if (s < CAP_) bucket[n * CAP_ + s] = d;
    else { int o = atomicAdd(ovfc, 1); if (o < OVF_MAX) ovf[o] = d; }
}

// ---------------------------------------------------------------------------
// Fused gather + einsum + relu -> h  (streaming float4 stores, NO atomics)
//   h[d,c] = relu( sum_{l,k} (vn*x[col[d,l]][k] + ve*ef[k]) * W[k,c,l] + b[c] )
// Software-pipelined: col chain 2 deep; x-row + W chunk for l+1 staged in
// registers during compute of l.
__global__ __launch_bounds__(256) void k_lrp(const float* __restrict__ x,
                                             const int*   __restrict__ n2p_col,
                                             const float* __restrict__ n2p_val,
                                             const float* __restrict__ e2p_val,
                                             const float* __restrict__ edge_W,
                                             const float* __restrict__ edge_b,
                                             const float* __restrict__ Wt,   // [16][64][64]
                                             const float* __restrict__ bl,   // [64]
                                             float* __restrict__ hout) {
    __shared__ float Tl[64][128];   // [k][d]
    __shared__ float Wl[64 * 64];   // [k][c]
    __shared__ float efs[64];
    int tid = threadIdx.x;
    int tx = tid & 15;              // c-group
    int ty = tid >> 4;              // d-group
    int d0 = blockIdx.x * 128;
    int dl = tid >> 1;              // fill row
    int kq = tid & 1;               // fill k-half
    int dg = d0 + dl;
    int dsafe = (dg < NPERM_) ? dg : 0;
    size_t pbase = (size_t)dsafe * 16;

    if (tid < 64) efs[tid] = edge_W[tid] + edge_b[tid];

    float acc[8][4];
#pragma unroll
    for (int m = 0; m < 8; ++m)
#pragma unroll
        for (int n = 0; n < 4; ++n) acc[m][n] = 0.f;

    float4 wv[4], xv[8];
    int   colN2 = n2p_col[pbase + 1];
    float vnN   = n2p_val[pbase + 0];
    float veN   = e2p_val[pbase + 0];
    {
        int col0 = n2p_col[pbase + 0];
        const float4* ws0 = (const float4*)Wt;
#pragma unroll
        for (int t = 0; t < 4; ++t) wv[t] = ws0[t * 256 + tid];
        const float4* xr = (const float4*)(x + (size_t)col0 * 64 + kq * 32);
#pragma unroll
        for (int j = 0; j < 8; ++j) xv[j] = xr[j];
    }
    __syncthreads();   // efs visible

    for (int l = 0; l < L_; ++l) {
        float vn = vnN, ve = veN;
        __syncthreads();           // previous compute done
        {
            float4* wd = (float4*)Wl;
#pragma unroll
            for (int t = 0; t < 4; ++t) wd[t * 256 + tid] = wv[t];
#pragma unroll
            for (int j = 0; j < 8; ++j) {
                int kb = kq * 32 + j * 4;
                float4 v = xv[j];
                Tl[kb + 0][dl] = fmaf(vn, v.x, ve * efs[kb + 0]);
                Tl[kb + 1][dl] = fmaf(vn, v.y, ve * efs[kb + 1]);
                Tl[kb + 2][dl] = fmaf(vn, v.z, ve * efs[kb + 2]);
                Tl[kb + 3][dl] = fmaf(vn, v.w, ve * efs[kb + 3]);
            }
        }
        __syncthreads();           // tiles visible
        if (l < 15) {              // prefetch next l under compute
            const float4* ws2 = (const float4*)(Wt + (l + 1) * 4096);
#pragma unroll
            for (int t = 0; t < 4; ++t) wv[t] = ws2[t * 256 + tid];
            const float4* xr = (const float4*)(x + (size_t)colN2 * 64 + kq * 32);
#pragma unroll
            for (int j = 0; j < 8; ++j) xv[j] = xr[j];
            vnN = n2p_val[pbase + l + 1];
            veN = e2p_val[pbase + l + 1];
            if (l < 14) colN2 = n2p_col[pbase + l + 2];
        }
#pragma unroll 4
        for (int k = 0; k < 64; ++k) {
            float4 w4 = *(const float4*)(Wl + k * 64 + tx * 4);
            float4 ta = *(const float4*)(&Tl[k][ty * 8]);
            float4 tb = *(const float4*)(&Tl[k][ty * 8 + 4]);
#pragma unroll
            for (int n = 0; n < 4; ++n) {
                float w = (n == 0) ? w4.x : (n == 1) ? w4.y : (n == 2) ? w4.z : w4.w;
                acc[0][n] = fmaf(ta.x, w, acc[0][n]);
                acc[1][n] = fmaf(ta.y, w, acc[1][n]);
                acc[2][n] = fmaf(ta.z, w, acc[2][n]);
                acc[3][n] = fmaf(ta.w, w, acc[3][n]);
                acc[4][n] = fmaf(tb.x, w, acc[4][n]);
                acc[5][n] = fmaf(tb.y, w, acc[5][n]);
                acc[6][n] = fmaf(tb.z, w, acc[6][n]);
                acc[7][n] = fmaf(tb.w, w, acc[7][n]);
            }
        }
    }
    // epilogue: relu + coalesced h store
    float4 bb = *(const float4*)(bl + tx * 4);
#pragma unroll
    for (int m = 0; m < 8; ++m) {
        int dd = d0 + ty * 8 + m;
        if (dd < NPERM_) {
            float4 o;
            o.x = fmaxf(acc[m][0] + bb.x, 0.f);
            o.y = fmaxf(acc[m][1] + bb.y, 0.f);
            o.z = fmaxf(acc[m][2] + bb.z, 0.f);
            o.w = fmaxf(acc[m][3] + bb.w, 0.f);
            *(float4*)(hout + (size_t)dd * 64 + tx * 4) = o;
        }
    }
}

// ---------------------------------------------------------------------------
// x[n] = ( sum_{d in bucket(n)} pool_val[d]*h[d] ) * (relu(degs[n]*A+Bb) @ W1 + b1)
// GEMM tile: 64 nodes x 64 c, K=128; pooling is a per-node bucket gather.
__global__ __launch_bounds__(256) void k_pool_factor(const float* __restrict__ h,
                                                     const int*   __restrict__ cntn,
                                                     const int*   __restrict__ bucket,
                                                     const int*   __restrict__ ovf,
                                                     const int*   __restrict__ ovfc,
                                                     const int*   __restrict__ prow,
                                                     const float* __restrict__ pval,
                                                     float* __restrict__ x,
                                                     const float* __restrict__ degs,
                                                     const float* __restrict__ A,
                                                     const float* __restrict__ Bb,
                                                     const float* __restrict__ W1,
                                                     const float* __restrict__ b1) {
    __shared__ float Hl[128][64];
    __shared__ float Wl[128 * 64];
    int tid = threadIdx.x;
    int tx = tid & 15, ty = tid >> 4;
    int d0 = blockIdx.x * 64;
    {
        const float4* src = (const float4*)W1;
        float4*       dst = (float4*)Wl;
#pragma unroll
        for (int t = 0; t < 8; ++t) dst[t * 256 + tid] = src[t * 256 + tid];
    }
    int dl = tid >> 2, jq = tid & 3;
    int n = d0 + dl;
    float dg = (n < N_NODES) ? degs[n] : 0.f;
#pragma unroll
    for (int jj = 0; jj < 32; ++jj) {
        int j = jq * 32 + jj;
        Hl[j][dl] = fmaxf(fmaf(dg, A[j], Bb[j]), 0.f);
    }
    __syncthreads();
    float acc[4][4];
#pragma unroll
    for (int m = 0; m < 4; ++m)
#pragma unroll
        for (int q = 0; q < 4; ++q) acc[m][q] = 0.f;
#pragma unroll 4
    for (int k = 0; k < 128; ++k) {
        float4 w4 = *(const float4*)(Wl + k * 64 + tx * 4);
        float4 t4 = *(const float4*)(&Hl[k][ty * 4]);
#pragma unroll
        for (int q = 0; q < 4; ++q) {
            float w = (q == 0) ? w4.x : (q == 1) ? w4.y : (q == 2) ? w4.z : w4.w;
            acc[0][q] = fmaf(t4.x, w, acc[0][q]);
            acc[1][q] = fmaf(t4.y, w, acc[1][q]);
            acc[2][q] = fmaf(t4.z, w, acc[2][q]);
            acc[3][q] = fmaf(t4.w, w, acc[3][q]);
        }
    }
    float4 bb = *(const float4*)(b1 + tx * 4);
    int novf = *ovfc;
#pragma unroll
    for (int m = 0; m < 4; ++m) {
        int nn = d0 + ty * 4 + m;
        if (nn >= N_NODES) continue;
        float4 p = make_float4(0.f, 0.f, 0.f, 0.f);
        int cn = min(cntn[nn], CAP_);
        for (int j = 0; j < cn; ++j) {
            int   d  = bucket[nn * CAP_ + j];
            float pv = pval[d];
            float4 hv = *(const float4*)(h + (size_t)d * 64 + tx * 4);
            p.x = fmaf(pv, hv.x, p.x);
            p.y = fmaf(pv, hv.y, p.y);
            p.z = fmaf(pv, hv.z, p.z);
            p.w = fmaf(pv, hv.w, p.w);
        }
        if (novf > 0) {   // expected never; correctness net
            int ne = novf < OVF_MAX ? novf : OVF_MAX;
            for (int e = 0; e < ne; ++e) {
                int d = ovf[e];
                if (prow[d] == nn) {
                    float pv = pval[d];
                    float4 hv = *(const float4*)(h + (size_t)d * 64 + tx * 4);
                    p.x = fmaf(pv, hv.x, p.x);
                    p.y = fmaf(pv, hv.y, p.y);
                    p.z = fmaf(pv, hv.z, p.z);
                    p.w = fmaf(pv, hv.w, p.w);
                }
            }
        }
        float4 xo;
        xo.x = p.x * (acc[m][0] + bb.x);
        xo.y = p.y * (acc[m][1] + bb.y);
        xo.z = p.z * (acc[m][2] + bb.z);
        xo.w = p.w * (acc[m][3] + bb.w);
        *(float4*)(x + (size_t)nn * 64 + tx * 4) = xo;
    }
}

// ---------------------------------------------------------------------------
// Segmented mean-pool over sorted batch: one atomic per graph boundary.
__global__ __launch_bounds__(256) void k_gpool(const float* __restrict__ x,
                                               const int* __restrict__ batch,
                                               float* __restrict__ out,
                                               float* __restrict__ cnt) {
    int wave = (blockIdx.x * 256 + threadIdx.x) >> 6;
    int lane = threadIdx.x & 63;
    int n0 = wave * 64;
    if (n0 >= N_NODES) return;
    int n1 = min(n0 + 64, N_NODES);
    int g = batch[n0];
    float s = 0.f, c = 0.f;
    for (int n = n0; n < n1; ++n) {
        int gn = batch[n];
        if (gn != g) {
            atomicAdd(out + (size_t)g * 64 + lane, s);
            if (lane == 0) atomicAdd(cnt + g, c);
            s = 0.f; c = 0.f; g = gn;
        }
        s += x[(size_t)n * 64 + lane];
        c += 1.f;
    }
    atomicAdd(out + (size_t)g * 64 + lane, s);
    if (lane == 0) atomicAdd(cnt + g, c);
}

__global__ __launch_bounds__(256) void k_gdiv(float* __restrict__ out,
                                              const float* __restrict__ cnt) {
    int idx = blockIdx.x * 256 + threadIdx.x;
    if (idx >= G_ * 64) return;
    out[idx] /= fmaxf(cnt[idx >> 6], 1.f);
}

// ---------------------------------------------------------------------------
extern "C" void kernel_launch(void* const* d_in, const int* in_sizes, int n_in,
                              void* d_out, int out_size, void* d_ws, size_t ws_size,
                              hipStream_t stream) {
    const float* node_feat = (const float*)d_in[0];
    const float* degs      = (const float*)d_in[1];
    const int*   batch     = (const int*)  d_in[2];
    const int*   n2p_col   = (const int*)  d_in[4];
    const float* n2p_val   = (const float*)d_in[5];
    const float* e2p_val   = (const float*)d_in[8];
    const int*   pool_row  = (const int*)  d_in[9];
    const float* pool_val  = (const float*)d_in[11];
    const float* atom_W    = (const float*)d_in[12];
    const float* atom_b    = (const float*)d_in[13];
    const float* edge_W    = (const float*)d_in[14];
    const float* edge_b    = (const float*)d_in[15];
    const float* W_lrp     = (const float*)d_in[16];
    const float* b_lrp     = (const float*)d_in[17];
    const float* dn0_W     = (const float*)d_in[18];
    const float* dn0_b     = (const float*)d_in[19];
    const float* dn1_W     = (const float*)d_in[20];
    const float* dn1_b     = (const float*)d_in[21];

    char* ws = (char*)d_ws;
    float* x      = (float*)(ws);                      // 25,600,000
    float* h      = (float*)(ws + 25600000);           // 25,600,000
    float* Wt     = (float*)(ws + 51200000);           // 1,048,576
    int*   bucket = (int*)  (ws + 52248576);           // 9,600,000
    int*   cntn   = (int*)  (ws + 61848576);           // 400,000
    int*   ovf    = (int*)  (ws + 62248576);           // 16,384
    int*   ovfc   = (int*)  (ws + 62264960);           // 128
    float* cntg   = (float*)(ws + 62265088);           // 4,096

    hipLaunchKernelGGL(k_transpose_w, dim3(1024), dim3(256), 0, stream, W_lrp, Wt);
    hipLaunchKernelGGL(k_atom, dim3(25000), dim3(256), 0, stream,
                       node_feat, atom_W, atom_b, x);
    // bucket build (once; pool_row is layer-invariant)
    hipMemsetAsync(cntn, 0, 400000, stream);
    hipMemsetAsync(ovfc, 0, 128, stream);
    hipLaunchKernelGGL(k_bucket, dim3(391), dim3(256), 0, stream,
                       pool_row, cntn, bucket, ovf, ovfc);
    for (int i = 0; i < 4; ++i) {
        hipLaunchKernelGGL(k_lrp, dim3(782), dim3(256), 0, stream,
                           x, n2p_col, n2p_val, e2p_val, edge_W, edge_b,
                           Wt + (size_t)i * 65536, b_lrp + i * 64, h);
        hipLaunchKernelGGL(k_pool_factor, dim3(1563), dim3(256), 0, stream,
                           h, cntn, bucket, ovf, ovfc, pool_row, pool_val,
                           x, degs, dn0_W + i * 128, dn0_b + i * 128,
                           dn1_W + i * 8192, dn1_b + i * 64);
    }
    hipMemsetAsync(d_out, 0, (size_t)G_ * 64 * 4, stream);
    hipMemsetAsync(cntg, 0, G_ * 4, stream);
    hipLaunchKernelGGL(k_gpool, dim3(391), dim3(256), 0, stream,
                       x, batch, (float*)d_out, cntg);
    hipLaunchKernelGGL(k_gdiv, dim3(256), dim3(256), 0, stream,
                       (float*)d_out, cntg);
}

// Round 6
// 921.478 us; speedup vs baseline: 1.6171x; 1.5305x over previous
//
#include <hip/hip_runtime.h>

typedef __attribute__((ext_vector_type(8))) short bf16x8;
typedef __attribute__((ext_vector_type(4))) float f32x4;

#define N_NODES   100000
#define NPERM_    100000
#define L_        16
#define G_        1024
#define CAP_      24
#define OVF_MAX   4096

__device__ inline unsigned short f32_to_bf16(float f) {
    unsigned u = __float_as_uint(f);
    unsigned r = (u + 0x7fff + ((u >> 16) & 1)) >> 16;   // RNE
    return (unsigned short)r;
}
__device__ inline float bflo(unsigned u) { return __uint_as_float(u << 16); }
__device__ inline float bfhi(unsigned u) { return __uint_as_float(u & 0xffff0000u); }
__device__ inline unsigned pk2(float a, float b) {
    return (unsigned)f32_to_bf16(a) | ((unsigned)f32_to_bf16(b) << 16);
}

// ---------------------------------------------------------------------------
// W_lrp [4][64 k][64 c][16 l] -> split bf16, layout [4][16 l][64 c][64 k]
// (B-frag = 8 consecutive k for one col -> c-major rows of k)
__global__ __launch_bounds__(256) void k_prep_w(const float* __restrict__ W,
                                                unsigned short* __restrict__ Wh,
                                                unsigned short* __restrict__ Wl) {
    int o = blockIdx.x * 256 + threadIdx.x;   // 262144
    int k = o & 63, c = (o >> 6) & 63, l = (o >> 12) & 15, i = o >> 16;
    float f = W[(((i * 64 + k) * 64) + c) * 16 + l];
    unsigned short hh = f32_to_bf16(f);
    float fl = f - bflo((unsigned)hh << 16 >> 16 << 16);  // f - upcast(hh)
    // simpler: recompute
    fl = f - __uint_as_float(((unsigned)hh) << 16);
    Wh[o] = hh;
    Wl[o] = f32_to_bf16(fl);
}

// ---------------------------------------------------------------------------
// x = node_feat @ atom_W + atom_b ;  also writes bf16 shadow xb
__global__ __launch_bounds__(256) void k_atom(const float* __restrict__ feat,
                                              const float* __restrict__ W,
                                              const float* __restrict__ b,
                                              float* __restrict__ x,
                                              unsigned short* __restrict__ xb) {
    __shared__ float Wlds[28 * 64];
    __shared__ float blds[64];
    int tid = threadIdx.x;
    for (int t = tid; t < 28 * 64; t += 256) Wlds[t] = W[t];
    if (tid < 64) blds[tid] = b[tid];
    __syncthreads();
    int n = blockIdx.x * 4 + (tid >> 6);
    int c = tid & 63;
    if (n >= N_NODES) return;
    const float* fr = feat + n * 28;
    float acc = blds[c];
#pragma unroll
    for (int j = 0; j < 28; ++j) acc = fmaf(fr[j], Wlds[j * 64 + c], acc);
    x[n * 64 + c] = acc;
    xb[n * 64 + c] = f32_to_bf16(acc);
}

// ---------------------------------------------------------------------------
__global__ __launch_bounds__(256) void k_bucket(const int* __restrict__ prow,
                                                int* __restrict__ cntn,
                                                int* __restrict__ bucket,
                                                int* __restrict__ ovf,
                                                int* __restrict__ ovfc) {
    int d = blockIdx.x * 256 + threadIdx.x;
    if (d >= NPERM_) return;
    int n = prow[d];
    int s = atomicAdd(cntn + n, 1);
    if (s < CAP_) bucket[n * CAP_ + s] = d;
    else { int o = atomicAdd(ovfc, 1); if (o < OVF_MAX) ovf[o] = d; }
}

// ---------------------------------------------------------------------------
// MFMA gather-GEMM:  h = relu( T(gather,bf16) @ (Whi+Wlo) + b )
// Block: 128 d x 64 c, 4 waves (each wave: 32 d x 64 c = 2x4 16x16 tiles).
// K = 16 l x 64 k; per l: stage T rows (bf16) + W chunk into padded LDS.
__global__ __launch_bounds__(256, 4) void k_lrp(const unsigned short* __restrict__ xb,
                                                const int*   __restrict__ n2p_col,
                                                const float* __restrict__ n2p_val,
                                                const float* __restrict__ e2p_val,
                                                const float* __restrict__ edge_W,
                                                const float* __restrict__ edge_b,
                                                const unsigned short* __restrict__ Wth, // [16][64][64]
                                                const unsigned short* __restrict__ Wtl,
                                                const float* __restrict__ bl,
                                                float* __restrict__ hout) {
    __shared__ unsigned short Tb[128][72];   // row stride 144 B (pad kills bank conflict)
    __shared__ unsigned short Wh[64][72];
    __shared__ unsigned short Wo[64][72];
    __shared__ float efs[64];
    int tid = threadIdx.x;
    int lane = tid & 63;
    int w = tid >> 6;               // wave id
    int d0 = blockIdx.x * 128;
    int dl = tid >> 1;              // T-fill row 0..127
    int kq = tid & 1;               // T-fill k-half
    int wc = tid >> 2;              // W-fill row (c) 0..63
    int wk = (tid & 3) * 16;        // W-fill k offset
    int dg = d0 + dl;
    int dsafe = (dg < NPERM_) ? dg : 0;
    size_t pbase = (size_t)dsafe * 16;

    if (tid < 64) efs[tid] = edge_W[tid] + edge_b[tid];

    f32x4 acc[2][4];
#pragma unroll
    for (int a = 0; a < 2; ++a)
#pragma unroll
        for (int cb = 0; cb < 4; ++cb) acc[a][cb] = (f32x4)0.f;

    // prologue: stage l=0; col chain 2 deep
    uint4 xv[4], wvh[2], wvl[2];
    int   colN2 = n2p_col[pbase + 1];
    float vnN   = n2p_val[pbase + 0];
    float veN   = e2p_val[pbase + 0];
    {
        int col0 = n2p_col[pbase + 0];
        const uint4* xr = (const uint4*)(xb + (size_t)col0 * 64 + kq * 32);
#pragma unroll
        for (int j = 0; j < 4; ++j) xv[j] = xr[j];
        const uint4* whr = (const uint4*)(Wth + wc * 64 + wk);
        wvh[0] = whr[0]; wvh[1] = whr[1];
        const uint4* wlr = (const uint4*)(Wtl + wc * 64 + wk);
        wvl[0] = wlr[0]; wvl[1] = wlr[1];
    }
    __syncthreads();   // efs visible

    for (int l = 0; l < L_; ++l) {
        float vn = vnN, ve = veN;
        __syncthreads();           // previous compute done, LDS reusable
        // ---- T fill: t = vn*x + ve*ef, rounded to bf16
#pragma unroll
        for (int j = 0; j < 4; ++j) {
            uint4 v = xv[j];
            int kb = kq * 32 + j * 8;
            float4 ea = *(const float4*)&efs[kb];
            float4 eb = *(const float4*)&efs[kb + 4];
            float t0 = fmaf(vn, bflo(v.x), ve * ea.x);
            float t1 = fmaf(vn, bfhi(v.x), ve * ea.y);
            float t2 = fmaf(vn, bflo(v.y), ve * ea.z);
            float t3 = fmaf(vn, bfhi(v.y), ve * ea.w);
            float t4 = fmaf(vn, bflo(v.z), ve * eb.x);
            float t5 = fmaf(vn, bfhi(v.z), ve * eb.y);
            float t6 = fmaf(vn, bflo(v.w), ve * eb.z);
            float t7 = fmaf(vn, bfhi(v.w), ve * eb.w);
            uint4 ow;
            ow.x = pk2(t0, t1); ow.y = pk2(t2, t3);
            ow.z = pk2(t4, t5); ow.w = pk2(t6, t7);
            *(uint4*)&Tb[dl][kb] = ow;
        }
        // ---- W fill (raw bf16 copy)
        *(uint4*)&Wh[wc][wk]     = wvh[0];
        *(uint4*)&Wh[wc][wk + 8] = wvh[1];
        *(uint4*)&Wo[wc][wk]     = wvl[0];
        *(uint4*)&Wo[wc][wk + 8] = wvl[1];
        __syncthreads();           // tiles visible
        if (l < 15) {              // prefetch l+1 under compute
            const uint4* whr = (const uint4*)(Wth + (l + 1) * 4096 + wc * 64 + wk);
            wvh[0] = whr[0]; wvh[1] = whr[1];
            const uint4* wlr = (const uint4*)(Wtl + (l + 1) * 4096 + wc * 64 + wk);
            wvl[0] = wlr[0]; wvl[1] = wlr[1];
            const uint4* xr = (const uint4*)(xb + (size_t)colN2 * 64 + kq * 32);
#pragma unroll
            for (int j = 0; j < 4; ++j) xv[j] = xr[j];
            vnN = n2p_val[pbase + l + 1];
            veN = e2p_val[pbase + l + 1];
            if (l < 14) colN2 = n2p_col[pbase + l + 2];
        }
        // ---- MFMA: 2 K-steps of 32
        {
            int r = lane & 15, q = lane >> 4;
#pragma unroll
            for (int s = 0; s < 2; ++s) {
                int ko = s * 32 + q * 8;
                bf16x8 a0 = *(const bf16x8*)&Tb[w * 32 + r][ko];
                bf16x8 a1 = *(const bf16x8*)&Tb[w * 32 + 16 + r][ko];
#pragma unroll
                for (int cb = 0; cb < 4; ++cb) {
                    bf16x8 bh = *(const bf16x8*)&Wh[cb * 16 + r][ko];
                    bf16x8 bo = *(const bf16x8*)&Wo[cb * 16 + r][ko];
                    acc[0][cb] = __builtin_amdgcn_mfma_f32_16x16x32_bf16(a0, bh, acc[0][cb], 0, 0, 0);
                    acc[0][cb] = __builtin_amdgcn_mfma_f32_16x16x32_bf16(a0, bo, acc[0][cb], 0, 0, 0);
                    acc[1][cb] = __builtin_amdgcn_mfma_f32_16x16x32_bf16(a1, bh, acc[1][cb], 0, 0, 0);
                    acc[1][cb] = __builtin_amdgcn_mfma_f32_16x16x32_bf16(a1, bo, acc[1][cb], 0, 0, 0);
                }
            }
        }
    }
    // epilogue: bias + relu, C/D layout col=lane&15, row=(lane>>4)*4+reg
    {
        int r = lane & 15, q = lane >> 4;
#pragma unroll
        for (int a = 0; a < 2; ++a)
#pragma unroll
            for (int cb = 0; cb < 4; ++cb) {
                float bias = bl[cb * 16 + r];
#pragma unroll
                for (int reg = 0; reg < 4; ++reg) {
                    int R = d0 + w * 32 + a * 16 + q * 4 + reg;
                    if (R < NPERM_)
                        hout[(size_t)R * 64 + cb * 16 + r] = fmaxf(acc[a][cb][reg] + bias, 0.f);
                }
            }
    }
}

// ---------------------------------------------------------------------------
// x[n] = (bucket-gather pool of h) * (relu(degs*A+Bb) @ W1 + b1);  + bf16 shadow
__global__ __launch_bounds__(256) void k_pool_factor(const float* __restrict__ h,
                                                     const int*   __restrict__ cntn,
                                                     const int*   __restrict__ bucket,
                                                     const int*   __restrict__ ovf,
                                                     const int*   __restrict__ ovfc,
                                                     const int*   __restrict__ prow,
                                                     const float* __restrict__ pval,
                                                     float* __restrict__ x,
                                                     unsigned short* __restrict__ xb,
                                                     const float* __restrict__ degs,
                                                     const float* __restrict__ A,
                                                     const float* __restrict__ Bb,
                                                     const float* __restrict__ W1,
                                                     const float* __restrict__ b1) {
    __shared__ float Hl[128][64];
    __shared__ float Wl[128 * 64];
    int tid = threadIdx.x;
    int tx = tid & 15, ty = tid >> 4;
    int d0 = blockIdx.x * 64;
    {
        const float4* src = (const float4*)W1;
        float4*       dst = (float4*)Wl;
#pragma unroll
        for (int t = 0; t < 8; ++t) dst[t * 256 + tid] = src[t * 256 + tid];
    }
    int dl = tid >> 2, jq = tid & 3;
    int n = d0 + dl;
    float dg = (n < N_NODES) ? degs[n] : 0.f;
#pragma unroll
    for (int jj = 0; jj < 32; ++jj) {
        int j = jq * 32 + jj;
        Hl[j][dl] = fmaxf(fmaf(dg, A[j], Bb[j]), 0.f);
    }
    __syncthreads();
    float acc[4][4];
#pragma unroll
    for (int m = 0; m < 4; ++m)
#pragma unroll
        for (int q = 0; q < 4; ++q) acc[m][q] = 0.f;
#pragma unroll 4
    for (int k = 0; k < 128; ++k) {
        float4 w4 = *(const float4*)(Wl + k * 64 + tx * 4);
        float4 t4 = *(const float4*)(&Hl[k][ty * 4]);
#pragma unroll
        for (int q = 0; q < 4; ++q) {
            float w = (q == 0) ? w4.x : (q == 1) ? w4.y : (q == 2) ? w4.z : w4.w;
            acc[0][q] = fmaf(t4.x, w, acc[0][q]);
            acc[1][q] = fmaf(t4.y, w, acc[1][q]);
            acc[2][q] = fmaf(t4.z, w, acc[2][q]);
            acc[3][q] = fmaf(t4.w, w, acc[3][q]);
        }
    }
    float4 bb = *(const float4*)(b1 + tx * 4);
    int novf = *ovfc;
#pragma unroll
    for (int m = 0; m < 4; ++m) {
        int nn = d0 + ty * 4 + m;
        if (nn >= N_NODES) continue;
        float4 p = make_float4(0.f, 0.f, 0.f, 0.f);
        int cn = min(cntn[nn], CAP_);
        for (int j = 0; j < cn; ++j) {
            int   d  = bucket[nn * CAP_ + j];
            float pv = pval[d];
            float4 hv = *(const float4*)(h + (size_t)d * 64 + tx * 4);
            p.x = fmaf(pv, hv.x, p.x);
            p.y = fmaf(pv, hv.y, p.y);
            p.z = fmaf(pv, hv.z, p.z);
            p.w = fmaf(pv, hv.w, p.w);
        }
        if (novf > 0) {
            int ne = novf < OVF_MAX ? novf : OVF_MAX;
            for (int e = 0; e < ne; ++e) {
                int d = ovf[e];
                if (prow[d] == nn) {
                    float pv = pval[d];
                    float4 hv = *(const float4*)(h + (size_t)d * 64 + tx * 4);
                    p.x = fmaf(pv, hv.x, p.x);
                    p.y = fmaf(pv, hv.y, p.y);
                    p.z = fmaf(pv, hv.z, p.z);
                    p.w = fmaf(pv, hv.w, p.w);
                }
            }
        }
        float4 xo;
        xo.x = p.x * (acc[m][0] + bb.x);
        xo.y = p.y * (acc[m][1] + bb.y);
        xo.z = p.z * (acc[m][2] + bb.z);
        xo.w = p.w * (acc[m][3] + bb.w);
        *(float4*)(x + (size_t)nn * 64 + tx * 4) = xo;
        ushort4 xbo;
        xbo.x = f32_to_bf16(xo.x);
        xbo.y = f32_to_bf16(xo.y);
        xbo.z = f32_to_bf16(xo.z);
        xbo.w = f32_to_bf16(xo.w);
        *(ushort4*)(xb + (size_t)nn * 64 + tx * 4) = xbo;
    }
}

// ---------------------------------------------------------------------------
__global__ __launch_bounds__(256) void k_gpool(const float* __restrict__ x,
                                               const int* __restrict__ batch,
                                               float* __restrict__ out,
                                               float* __restrict__ cnt) {
    int wave = (blockIdx.x * 256 + threadIdx.x) >> 6;
    int lane = threadIdx.x & 63;
    int n0 = wave * 64;
    if (n0 >= N_NODES) return;
    int n1 = min(n0 + 64, N_NODES);
    int g = batch[n0];
    float s = 0.f, c = 0.f;
    for (int n = n0; n < n1; ++n) {
        int gn = batch[n];
        if (gn != g) {
            atomicAdd(out + (size_t)g * 64 + lane, s);
            if (lane == 0) atomicAdd(cnt + g, c);
            s = 0.f; c = 0.f; g = gn;
        }
        s += x[(size_t)n * 64 + lane];
        c += 1.f;
    }
    atomicAdd(out + (size_t)g * 64 + lane, s);
    if (lane == 0) atomicAdd(cnt + g, c);
}

__global__ __launch_bounds__(256) void k_gdiv(float* __restrict__ out,
                                              const float* __restrict__ cnt) {
    int idx = blockIdx.x * 256 + threadIdx.x;
    if (idx >= G_ * 64) return;
    out[idx] /= fmaxf(cnt[idx >> 6], 1.f);
}

// ---------------------------------------------------------------------------
extern "C" void kernel_launch(void* const* d_in, const int* in_sizes, int n_in,
                              void* d_out, int out_size, void* d_ws, size_t ws_size,
                              hipStream_t stream) {
    const float* node_feat = (const float*)d_in[0];
    const float* degs      = (const float*)d_in[1];
    const int*   batch     = (const int*)  d_in[2];
    const int*   n2p_col   = (const int*)  d_in[4];
    const float* n2p_val   = (const float*)d_in[5];
    const float* e2p_val   = (const float*)d_in[8];
    const int*   pool_row  = (const int*)  d_in[9];
    const float* pool_val  = (const float*)d_in[11];
    const float* atom_W    = (const float*)d_in[12];
    const float* atom_b    = (const float*)d_in[13];
    const float* edge_W    = (const float*)d_in[14];
    const float* edge_b    = (const float*)d_in[15];
    const float* W_lrp     = (const float*)d_in[16];
    const float* b_lrp     = (const float*)d_in[17];
    const float* dn0_W     = (const float*)d_in[18];
    const float* dn0_b     = (const float*)d_in[19];
    const float* dn1_W     = (const float*)d_in[20];
    const float* dn1_b     = (const float*)d_in[21];

    char* ws = (char*)d_ws;
    float*          x      = (float*)         (ws);                // 25,600,000
    float*          h      = (float*)         (ws + 25600000);     // 25,600,000
    unsigned short* xb     = (unsigned short*)(ws + 51200000);     // 12,800,000
    unsigned short* Wth    = (unsigned short*)(ws + 64000000);     //    524,288
    unsigned short* Wtl    = (unsigned short*)(ws + 64524288);     //    524,288
    int*            bucket = (int*)           (ws + 65048576);     //  9,600,000
    int*            cntn   = (int*)           (ws + 74648576);     //    400,000
    int*            ovf    = (int*)           (ws + 75048576);     //     16,384
    int*            ovfc   = (int*)           (ws + 75064960);     //        128
    float*          cntg   = (float*)         (ws + 75065088);     //      4,096

    hipLaunchKernelGGL(k_prep_w, dim3(1024), dim3(256), 0, stream, W_lrp, Wth, Wtl);
    hipLaunchKernelGGL(k_atom, dim3(25000), dim3(256), 0, stream,
                       node_feat, atom_W, atom_b, x, xb);
    hipMemsetAsync(cntn, 0, 400000, stream);
    hipMemsetAsync(ovfc, 0, 128, stream);
    hipLaunchKernelGGL(k_bucket, dim3(391), dim3(256), 0, stream,
                       pool_row, cntn, bucket, ovf, ovfc);
    for (int i = 0; i < 4; ++i) {
        hipLaunchKernelGGL(k_lrp, dim3(782), dim3(256), 0, stream,
                           xb, n2p_col, n2p_val, e2p_val, edge_W, edge_b,
                           Wth + (size_t)i * 65536, Wtl + (size_t)i * 65536,
                           b_lrp + i * 64, h);
        hipLaunchKernelGGL(k_pool_factor, dim3(1563), dim3(256), 0, stream,
                           h, cntn, bucket, ovf, ovfc, pool_row, pool_val,
                           x, xb, degs, dn0_W + i * 128, dn0_b + i * 128,
                           dn1_W + i * 8192, dn1_b + i * 64);
    }
    hipMemsetAsync(d_out, 0, (size_t)G_ * 64 * 4, stream);
    hipMemsetAsync(cntg, 0, G_ * 4, stream);
    hipLaunchKernelGGL(k_gpool, dim3(391), dim3(256), 0, stream,
                       x, batch, (float*)d_out, cntg);
    hipLaunchKernelGGL(k_gdiv, dim3(256), dim3(256), 0, stream,
                       (float*)d_out, cntg);
}